// Round 5
// baseline (377.767 us; speedup 1.0000x reference)
//
#include <hip/hip_runtime.h>

#define N_NODES 100000
#define N_EDGES 3200000
#define IN_F 256
#define OUT_F 128
#define NREP 16

typedef __attribute__((ext_vector_type(8))) short bf16x8;
typedef __attribute__((ext_vector_type(4))) float f32x4;

__device__ inline unsigned short f2bf(float f) {
    union { float f; unsigned u; } v; v.f = f;
    unsigned r = v.u + 0x7FFFu + ((v.u >> 16) & 1u);   // round-to-nearest-even
    return (unsigned short)(r >> 16);
}
__device__ inline unsigned pk2(float a, float b) {
    return (unsigned)f2bf(a) | ((unsigned)f2bf(b) << 16);
}

// -------------------- Kernel 1: h = bf16(x @ w) via MFMA --------------------
__global__ __launch_bounds__(256) void gemm_xw_mfma(
    const float* __restrict__ x, const float* __restrict__ w,
    unsigned short* __restrict__ h)
{
    __shared__ unsigned short alds[128][40];
    __shared__ unsigned short blds[128][264];

    const int t    = threadIdx.x;
    const int lane = t & 63;
    const int wid  = t >> 6;
    const int brow = blockIdx.x * 128;
    const int ln   = lane & 15;
    const int kb   = lane >> 4;
    const int am   = wid * 32;

    {
        int c4 = (t & 31) * 4;
        int kr = (t >> 5) * 4;
#pragma unroll
        for (int kb2 = 0; kb2 < 8; ++kb2) {
            int kbase = kb2 * 32 + kr;
            float4 r0 = *(const float4*)(w + (size_t)(kbase + 0) * OUT_F + c4);
            float4 r1 = *(const float4*)(w + (size_t)(kbase + 1) * OUT_F + c4);
            float4 r2 = *(const float4*)(w + (size_t)(kbase + 2) * OUT_F + c4);
            float4 r3 = *(const float4*)(w + (size_t)(kbase + 3) * OUT_F + c4);
            *(uint2*)&blds[c4 + 0][kbase] = make_uint2(pk2(r0.x, r1.x), pk2(r2.x, r3.x));
            *(uint2*)&blds[c4 + 1][kbase] = make_uint2(pk2(r0.y, r1.y), pk2(r2.y, r3.y));
            *(uint2*)&blds[c4 + 2][kbase] = make_uint2(pk2(r0.z, r1.z), pk2(r2.z, r3.z));
            *(uint2*)&blds[c4 + 3][kbase] = make_uint2(pk2(r0.w, r1.w), pk2(r2.w, r3.w));
        }
    }

    f32x4 acc[2][8] = {};

    for (int k0 = 0; k0 < IN_F; k0 += 32) {
        {
            int r  = t >> 1;
            int kh = (t & 1) * 16;
            int gr = brow + r;
            float f[16];
#pragma unroll
            for (int i = 0; i < 16; ++i) f[i] = 0.f;
            if (gr < N_NODES) {
                const float* src = x + (size_t)gr * IN_F + k0 + kh;
                *(float4*)&f[0]  = ((const float4*)src)[0];
                *(float4*)&f[4]  = ((const float4*)src)[1];
                *(float4*)&f[8]  = ((const float4*)src)[2];
                *(float4*)&f[12] = ((const float4*)src)[3];
            }
            uint4 qa, qb;
            qa.x = pk2(f[0], f[1]);   qa.y = pk2(f[2], f[3]);
            qa.z = pk2(f[4], f[5]);   qa.w = pk2(f[6], f[7]);
            qb.x = pk2(f[8], f[9]);   qb.y = pk2(f[10], f[11]);
            qb.z = pk2(f[12], f[13]); qb.w = pk2(f[14], f[15]);
            *(uint4*)&alds[r][kh]     = qa;
            *(uint4*)&alds[r][kh + 8] = qb;
        }
        __syncthreads();

        bf16x8 a[2], b[8];
#pragma unroll
        for (int fm = 0; fm < 2; ++fm)
            a[fm] = *(const bf16x8*)&alds[am + fm * 16 + ln][kb * 8];
#pragma unroll
        for (int fn = 0; fn < 8; ++fn)
            b[fn] = *(const bf16x8*)&blds[fn * 16 + ln][k0 + kb * 8];

#pragma unroll
        for (int fm = 0; fm < 2; ++fm)
#pragma unroll
            for (int fn = 0; fn < 8; ++fn)
                acc[fm][fn] = __builtin_amdgcn_mfma_f32_16x16x32_bf16(
                    a[fm], b[fn], acc[fm][fn], 0, 0, 0);
        __syncthreads();
    }

#pragma unroll
    for (int fm = 0; fm < 2; ++fm) {
#pragma unroll
        for (int r = 0; r < 4; ++r) {
            int grow = brow + am + fm * 16 + (lane >> 4) * 4 + r;
            if (grow < N_NODES) {
                unsigned short* dst = h + (size_t)grow * OUT_F + ln;
#pragma unroll
                for (int fn = 0; fn < 8; ++fn)
                    dst[fn * 16] = f2bf(acc[fm][fn][r]);
            }
        }
    }
}

// -------------------- Kernel 2: replicated histogram + per-edge rank --------------------
// rep = tid & 15; rank[e] = old count within (rep, row).
__global__ __launch_bounds__(256) void hist_kernel(
    const int* __restrict__ erow, int* __restrict__ cnt16,
    unsigned short* __restrict__ rank)
{
    int tid = blockIdx.x * 256 + threadIdx.x;     // over N_EDGES/4
    if (tid >= N_EDGES / 4) return;
    int4 r = ((const int4*)erow)[tid];
    int* c = cnt16 + (tid & (NREP - 1)) * N_NODES;
    ushort4 rk;
    rk.x = (unsigned short)atomicAdd(&c[r.x], 1);
    rk.y = (unsigned short)atomicAdd(&c[r.y], 1);
    rk.z = (unsigned short)atomicAdd(&c[r.z], 1);
    rk.w = (unsigned short)atomicAdd(&c[r.w], 1);
    ((ushort4*)rank)[tid] = rk;
}

// -------------------- Kernel 2b: per-row totals over 16 replicas --------------------
__global__ __launch_bounds__(256) void rowtot_kernel(
    const int* __restrict__ cnt16, int* __restrict__ rowtot)
{
    int r = blockIdx.x * 256 + threadIdx.x;
    if (r >= N_NODES) return;
    int s = 0;
#pragma unroll
    for (int rep = 0; rep < NREP; ++rep) s += cnt16[rep * N_NODES + r];
    rowtot[r] = s;
}

// -------------------- Kernels 3a/3b/3c: 3-phase exclusive scan over rowtot --------------------
#define SCAN_CHUNK 1024
#define N_SCAN_BLKS ((N_NODES + SCAN_CHUNK - 1) / SCAN_CHUNK)   // 98

__global__ __launch_bounds__(256) void scan_phase1(
    const int* __restrict__ rowtot, int* __restrict__ partials)
{
    __shared__ int red[256];
    int t = threadIdx.x, b = blockIdx.x;
    int base = b * SCAN_CHUNK + t * 4;
    int s = 0;
#pragma unroll
    for (int i = 0; i < 4; ++i) {
        int idx = base + i;
        if (idx < N_NODES) s += rowtot[idx];
    }
    red[t] = s;
    __syncthreads();
    for (int off = 128; off > 0; off >>= 1) {
        if (t < off) red[t] += red[t + off];
        __syncthreads();
    }
    if (t == 0) partials[b] = red[0];
}

__global__ __launch_bounds__(128) void scan_phase2(int* __restrict__ partials)
{
    __shared__ int sh[128];
    int t = threadIdx.x;
    int v = (t < N_SCAN_BLKS) ? partials[t] : 0;
    sh[t] = v;
    __syncthreads();
    for (int off = 1; off < 128; off <<= 1) {
        int add = (t >= off) ? sh[t - off] : 0;
        __syncthreads();
        sh[t] += add;
        __syncthreads();
    }
    if (t < N_SCAN_BLKS) partials[t] = sh[t] - v;    // exclusive
}

__global__ __launch_bounds__(256) void scan_phase3(
    const int* __restrict__ rowtot, const int* __restrict__ partials,
    int* __restrict__ row_start)
{
    __shared__ int sh[256];
    int t = threadIdx.x, b = blockIdx.x;
    int base = b * SCAN_CHUNK + t * 4;
    int c[4];
    int s = 0;
#pragma unroll
    for (int i = 0; i < 4; ++i) {
        int idx = base + i;
        c[i] = (idx < N_NODES) ? rowtot[idx] : 0;
        s += c[i];
    }
    sh[t] = s;
    __syncthreads();
    for (int off = 1; off < 256; off <<= 1) {
        int add = (t >= off) ? sh[t - off] : 0;
        __syncthreads();
        sh[t] += add;
        __syncthreads();
    }
    int run = sh[t] - s + partials[b];
#pragma unroll
    for (int i = 0; i < 4; ++i) {
        int idx = base + i;
        if (idx < N_NODES) { row_start[idx] = run; run += c[i]; }
    }
}

// -------------------- Kernel 3d: per-(rep,row) base offsets --------------------
__global__ __launch_bounds__(256) void repbase_kernel(
    const int* __restrict__ cnt16, const int* __restrict__ row_start,
    int* __restrict__ repbase)
{
    int r = blockIdx.x * 256 + threadIdx.x;
    if (r >= N_NODES) return;
    int base = row_start[r];
#pragma unroll
    for (int rep = 0; rep < NREP; ++rep) {
        repbase[rep * N_NODES + r] = base;
        base += cnt16[rep * N_NODES + r];
    }
}

// -------------------- Kernel 4: atomic-free permute into CSR order --------------------
__global__ __launch_bounds__(256) void permute_kernel(
    const int* __restrict__ erow, const int* __restrict__ ecol,
    const float* __restrict__ eval_, const unsigned short* __restrict__ rank,
    const int* __restrict__ repbase, int2* __restrict__ packed)
{
    int e = blockIdx.x * 256 + threadIdx.x;
    if (e >= N_EDGES) return;
    int r   = erow[e];
    int rep = (e >> 2) & (NREP - 1);              // matches hist's tid = e/4
    int pos = repbase[rep * N_NODES + r] + (int)rank[e];
    packed[pos] = make_int2(ecol[e], __float_as_int(eval_[e]));
}

// -------------------- Kernel 5: per-row gather-aggregate + bias --------------------
__global__ __launch_bounds__(256) void aggregate_kernel(
    const int2* __restrict__ packed, const int* __restrict__ row_start,
    const int* __restrict__ rowtot, const unsigned* __restrict__ h2,
    const float* __restrict__ bias, float* __restrict__ out)
{
    int wave = (blockIdx.x * 256 + threadIdx.x) >> 6;
    int lane = threadIdx.x & 63;
    if (wave >= N_NODES) return;

    int start = __builtin_amdgcn_readfirstlane(row_start[wave]);
    int deg   = __builtin_amdgcn_readfirstlane(rowtot[wave]);
    int end   = start + deg;

    const unsigned* hb = h2 + lane;
    float ax = 0.f, ay = 0.f;

    int e = start;
    for (; e + 3 < end; e += 4) {
        int2 p0 = packed[e];
        int2 p1 = packed[e + 1];
        int2 p2 = packed[e + 2];
        int2 p3 = packed[e + 3];
        unsigned u0 = hb[(size_t)p0.x << 6];
        unsigned u1 = hb[(size_t)p1.x << 6];
        unsigned u2 = hb[(size_t)p2.x << 6];
        unsigned u3 = hb[(size_t)p3.x << 6];
        float v0 = __int_as_float(p0.y), v1 = __int_as_float(p1.y);
        float v2 = __int_as_float(p2.y), v3 = __int_as_float(p3.y);
        ax = fmaf(v0, __uint_as_float(u0 << 16), ax);
        ay = fmaf(v0, __uint_as_float(u0 & 0xFFFF0000u), ay);
        ax = fmaf(v1, __uint_as_float(u1 << 16), ax);
        ay = fmaf(v1, __uint_as_float(u1 & 0xFFFF0000u), ay);
        ax = fmaf(v2, __uint_as_float(u2 << 16), ax);
        ay = fmaf(v2, __uint_as_float(u2 & 0xFFFF0000u), ay);
        ax = fmaf(v3, __uint_as_float(u3 << 16), ax);
        ay = fmaf(v3, __uint_as_float(u3 & 0xFFFF0000u), ay);
    }
    for (; e < end; ++e) {
        int2 p0 = packed[e];
        unsigned u0 = hb[(size_t)p0.x << 6];
        float v0 = __int_as_float(p0.y);
        ax = fmaf(v0, __uint_as_float(u0 << 16), ax);
        ay = fmaf(v0, __uint_as_float(u0 & 0xFFFF0000u), ay);
    }

    float2 b = *(const float2*)(bias + lane * 2);
    *(float2*)(out + (size_t)wave * OUT_F + lane * 2) = make_float2(ax + b.x, ay + b.y);
}

// -------------------- launch --------------------
extern "C" void kernel_launch(void* const* d_in, const int* in_sizes, int n_in,
                              void* d_out, int out_size, void* d_ws, size_t ws_size,
                              hipStream_t stream)
{
    const float* x     = (const float*)d_in[0];
    const int*   erow  = (const int*)d_in[1];
    const int*   ecol  = (const int*)d_in[2];
    const float* eval_ = (const float*)d_in[3];
    const float* w     = (const float*)d_in[4];
    const float* bias  = (const float*)d_in[5];
    float*       out   = (float*)d_out;

    // workspace layout (bytes):
    //   h (bf16):  0            .. 25,600,000
    //   cnt16:     25,600,000   .. +6,400,000   (16 x 100K int, partition-major)
    //   rowtot:    32,000,000   .. +400,000
    //   row_start: 32,400,000   .. +400,000
    //   partials:  32,800,000   .. +4,096
    //   repbase:   32,804,096   .. +6,400,000
    //   rank:      39,204,096   .. +6,400,000   (ushort per edge)
    //   packed:    45,604,096   .. +25,600,000  (total ~71.2 MB)
    char* ws = (char*)d_ws;
    unsigned short* h         = (unsigned short*)(ws);
    int*            cnt16     = (int*)(ws + 25600000);
    int*            rowtot    = (int*)(ws + 32000000);
    int*            row_start = (int*)(ws + 32400000);
    int*            partials  = (int*)(ws + 32800000);
    int*            repbase   = (int*)(ws + 32804096);
    unsigned short* rank      = (unsigned short*)(ws + 39204096);
    int2*           packed    = (int2*)(ws + 45604096);

    hipMemsetAsync(cnt16, 0, NREP * N_NODES * sizeof(int), stream);

    // 1) h = bf16(x @ w) via MFMA
    hipLaunchKernelGGL(gemm_xw_mfma,
                       dim3((N_NODES + 127) / 128), dim3(256), 0, stream,
                       x, w, h);

    // 2) replicated histogram + rank
    hipLaunchKernelGGL(hist_kernel,
                       dim3((N_EDGES / 4 + 255) / 256), dim3(256), 0, stream,
                       erow, cnt16, rank);

    // 2b) per-row totals
    hipLaunchKernelGGL(rowtot_kernel,
                       dim3((N_NODES + 255) / 256), dim3(256), 0, stream,
                       cnt16, rowtot);

    // 3) exclusive scan -> row_start
    hipLaunchKernelGGL(scan_phase1, dim3(N_SCAN_BLKS), dim3(256), 0, stream, rowtot, partials);
    hipLaunchKernelGGL(scan_phase2, dim3(1), dim3(128), 0, stream, partials);
    hipLaunchKernelGGL(scan_phase3, dim3(N_SCAN_BLKS), dim3(256), 0, stream,
                       rowtot, partials, row_start);

    // 3d) per-(rep,row) bases
    hipLaunchKernelGGL(repbase_kernel,
                       dim3((N_NODES + 255) / 256), dim3(256), 0, stream,
                       cnt16, row_start, repbase);

    // 4) atomic-free permute into CSR order
    hipLaunchKernelGGL(permute_kernel,
                       dim3((N_EDGES + 255) / 256), dim3(256), 0, stream,
                       erow, ecol, eval_, rank, repbase, packed);

    // 5) aggregate rows + bias
    hipLaunchKernelGGL(aggregate_kernel,
                       dim3((N_NODES * 64 + 255) / 256), dim3(256), 0, stream,
                       packed, row_start, rowtot, (const unsigned*)h, bias, out);
}

// Round 6
// 253.836 us; speedup vs baseline: 1.4882x; 1.4882x over previous
//
#include <hip/hip_runtime.h>

#define N_NODES 100000
#define N_EDGES 3200000
#define IN_F 256
#define OUT_F 128

#define NBIN 391          // coarse bins: row >> 8  (99999>>8 = 390)
#define NBC  512          // coarse pass blocks
#define CHUNK 6250        // edges per coarse block (512*6250 = 3.2M exactly)

typedef __attribute__((ext_vector_type(8))) short bf16x8;
typedef __attribute__((ext_vector_type(4))) float f32x4;

__device__ inline unsigned short f2bf(float f) {
    union { float f; unsigned u; } v; v.f = f;
    unsigned r = v.u + 0x7FFFu + ((v.u >> 16) & 1u);   // round-to-nearest-even
    return (unsigned short)(r >> 16);
}
__device__ inline unsigned pk2(float a, float b) {
    return (unsigned)f2bf(a) | ((unsigned)f2bf(b) << 16);
}

// -------------------- Kernel 1: h = bf16(x @ w) via MFMA --------------------
__global__ __launch_bounds__(256) void gemm_xw_mfma(
    const float* __restrict__ x, const float* __restrict__ w,
    unsigned short* __restrict__ h)
{
    __shared__ unsigned short alds[128][40];
    __shared__ unsigned short blds[128][264];

    const int t    = threadIdx.x;
    const int lane = t & 63;
    const int wid  = t >> 6;
    const int brow = blockIdx.x * 128;
    const int ln   = lane & 15;
    const int kb   = lane >> 4;
    const int am   = wid * 32;

    {
        int c4 = (t & 31) * 4;
        int kr = (t >> 5) * 4;
#pragma unroll
        for (int kb2 = 0; kb2 < 8; ++kb2) {
            int kbase = kb2 * 32 + kr;
            float4 r0 = *(const float4*)(w + (size_t)(kbase + 0) * OUT_F + c4);
            float4 r1 = *(const float4*)(w + (size_t)(kbase + 1) * OUT_F + c4);
            float4 r2 = *(const float4*)(w + (size_t)(kbase + 2) * OUT_F + c4);
            float4 r3 = *(const float4*)(w + (size_t)(kbase + 3) * OUT_F + c4);
            *(uint2*)&blds[c4 + 0][kbase] = make_uint2(pk2(r0.x, r1.x), pk2(r2.x, r3.x));
            *(uint2*)&blds[c4 + 1][kbase] = make_uint2(pk2(r0.y, r1.y), pk2(r2.y, r3.y));
            *(uint2*)&blds[c4 + 2][kbase] = make_uint2(pk2(r0.z, r1.z), pk2(r2.z, r3.z));
            *(uint2*)&blds[c4 + 3][kbase] = make_uint2(pk2(r0.w, r1.w), pk2(r2.w, r3.w));
        }
    }

    f32x4 acc[2][8] = {};

    for (int k0 = 0; k0 < IN_F; k0 += 32) {
        {
            int r  = t >> 1;
            int kh = (t & 1) * 16;
            int gr = brow + r;
            float f[16];
#pragma unroll
            for (int i = 0; i < 16; ++i) f[i] = 0.f;
            if (gr < N_NODES) {
                const float* src = x + (size_t)gr * IN_F + k0 + kh;
                *(float4*)&f[0]  = ((const float4*)src)[0];
                *(float4*)&f[4]  = ((const float4*)src)[1];
                *(float4*)&f[8]  = ((const float4*)src)[2];
                *(float4*)&f[12] = ((const float4*)src)[3];
            }
            uint4 qa, qb;
            qa.x = pk2(f[0], f[1]);   qa.y = pk2(f[2], f[3]);
            qa.z = pk2(f[4], f[5]);   qa.w = pk2(f[6], f[7]);
            qb.x = pk2(f[8], f[9]);   qb.y = pk2(f[10], f[11]);
            qb.z = pk2(f[12], f[13]); qb.w = pk2(f[14], f[15]);
            *(uint4*)&alds[r][kh]     = qa;
            *(uint4*)&alds[r][kh + 8] = qb;
        }
        __syncthreads();

        bf16x8 a[2], b[8];
#pragma unroll
        for (int fm = 0; fm < 2; ++fm)
            a[fm] = *(const bf16x8*)&alds[am + fm * 16 + ln][kb * 8];
#pragma unroll
        for (int fn = 0; fn < 8; ++fn)
            b[fn] = *(const bf16x8*)&blds[fn * 16 + ln][k0 + kb * 8];

#pragma unroll
        for (int fm = 0; fm < 2; ++fm)
#pragma unroll
            for (int fn = 0; fn < 8; ++fn)
                acc[fm][fn] = __builtin_amdgcn_mfma_f32_16x16x32_bf16(
                    a[fm], b[fn], acc[fm][fn], 0, 0, 0);
        __syncthreads();
    }

#pragma unroll
    for (int fm = 0; fm < 2; ++fm) {
#pragma unroll
        for (int r = 0; r < 4; ++r) {
            int grow = brow + am + fm * 16 + (lane >> 4) * 4 + r;
            if (grow < N_NODES) {
                unsigned short* dst = h + (size_t)grow * OUT_F + ln;
#pragma unroll
                for (int fn = 0; fn < 8; ++fn)
                    dst[fn * 16] = f2bf(acc[fm][fn][r]);
            }
        }
    }
}

// -------------------- Pass A: coarse LDS histogram per block --------------------
// Block b counts bins (row>>8) of its CHUNK edges; writes cntmat[b][bin].
__global__ __launch_bounds__(256) void pass_a_kernel(
    const int* __restrict__ erow, int* __restrict__ cntmat)
{
    __shared__ int lhist[512];
    const int t = threadIdx.x;
    const int b = blockIdx.x;
    lhist[t] = 0; lhist[t + 256] = 0;
    __syncthreads();

    const int base = b * CHUNK;
    for (int i = t; i < CHUNK; i += 256)
        atomicAdd(&lhist[erow[base + i] >> 8], 1);
    __syncthreads();

    int* dst = cntmat + (size_t)b * NBIN;
    for (int j = t; j < NBIN; j += 256) dst[j] = lhist[j];
}

// -------------------- Pass B: per-bin exclusive scan over 512 blocks --------------------
// Block j: blockbase[b][j] = sum_{b'<b} cntmat[b'][j];  tot[j] = column total.
__global__ __launch_bounds__(256) void pass_b_kernel(
    const int* __restrict__ cntmat, int* __restrict__ blockbase,
    int* __restrict__ tot)
{
    __shared__ int sh[256];
    const int t = threadIdx.x;
    const int j = blockIdx.x;
    const int b0 = 2 * t, b1 = 2 * t + 1;
    int c0 = cntmat[(size_t)b0 * NBIN + j];
    int c1 = cntmat[(size_t)b1 * NBIN + j];
    int ps = c0 + c1;
    sh[t] = ps;
    __syncthreads();
    for (int off = 1; off < 256; off <<= 1) {
        int add = (t >= off) ? sh[t - off] : 0;
        __syncthreads();
        sh[t] += add;
        __syncthreads();
    }
    int excl = sh[t] - ps;
    blockbase[(size_t)b0 * NBIN + j] = excl;
    blockbase[(size_t)b1 * NBIN + j] = excl + c0;
    if (t == 255) tot[j] = sh[255];
}

// -------------------- Pass B2: exclusive scan of bucket totals --------------------
__global__ __launch_bounds__(512) void pass_b2_kernel(
    const int* __restrict__ tot, int* __restrict__ bucket_base)
{
    __shared__ int sh[512];
    const int t = threadIdx.x;
    int v = (t < NBIN) ? tot[t] : 0;
    sh[t] = v;
    __syncthreads();
    for (int off = 1; off < 512; off <<= 1) {
        int add = (t >= off) ? sh[t - off] : 0;
        __syncthreads();
        sh[t] += add;
        __syncthreads();
    }
    if (t < NBIN + 1) bucket_base[t] = sh[t] - v;   // exclusive; [NBIN] = N_EDGES
}

// -------------------- Pass C: scatter edges into coarse buckets --------------------
// Block b's cursor for bin j starts at bucket_base[j] + blockbase[b][j]:
// globally disjoint ranges -> LDS atomics only.
__global__ __launch_bounds__(256) void pass_c_kernel(
    const int* __restrict__ erow, const int* __restrict__ ecol,
    const float* __restrict__ eval_, const int* __restrict__ blockbase,
    const int* __restrict__ bucket_base, int2* __restrict__ tmp)
{
    __shared__ int cur[NBIN];
    const int t = threadIdx.x;
    const int b = blockIdx.x;
    for (int j = t; j < NBIN; j += 256)
        cur[j] = bucket_base[j] + blockbase[(size_t)b * NBIN + j];
    __syncthreads();

    const int base = b * CHUNK;
    for (int i = t; i < CHUNK; i += 256) {
        int e = base + i;
        int r = erow[e];
        int c = ecol[e];
        float v = eval_[e];
        int pos = atomicAdd(&cur[r >> 8], 1);
        tmp[pos] = make_int2(c | ((r & 255) << 17), __float_as_int(v));
    }
}

// -------------------- Pass D: fine sort within bucket -> CSR + row_start/rowtot ----
// One block per bucket (256 fine rows, ~8.2K edges).
__global__ __launch_bounds__(256) void pass_d_kernel(
    const int2* __restrict__ tmp, const int* __restrict__ bucket_base,
    int2* __restrict__ packed, int* __restrict__ row_start,
    int* __restrict__ rowtot)
{
    __shared__ int hist[256];
    __shared__ int cursor[256];
    const int t = threadIdx.x;
    const int j = blockIdx.x;
    const int base = bucket_base[j];
    const int end  = bucket_base[j + 1];

    hist[t] = 0;
    __syncthreads();

    // phase 1: fine histogram
    for (int i = base + t; i < end; i += 256)
        atomicAdd(&hist[tmp[i].x >> 17], 1);
    __syncthreads();

    // exclusive scan of hist (Hillis-Steele in cursor)
    int hv = hist[t];
    cursor[t] = hv;
    __syncthreads();
    for (int off = 1; off < 256; off <<= 1) {
        int add = (t >= off) ? cursor[t - off] : 0;
        __syncthreads();
        cursor[t] += add;
        __syncthreads();
    }
    int excl = cursor[t] - hv;

    int r = j * 256 + t;
    if (r < N_NODES) {
        row_start[r] = base + excl;
        rowtot[r]    = hv;
    }
    __syncthreads();
    cursor[t] = excl;
    __syncthreads();

    // phase 2: scatter into final CSR order (tmp is L3-hot)
    for (int i = base + t; i < end; i += 256) {
        int2 p = tmp[i];
        int rl = p.x >> 17;
        int pos = atomicAdd(&cursor[rl], 1);
        packed[base + pos] = make_int2(p.x & 0x1FFFF, p.y);
    }
}

// -------------------- Kernel 5: per-row gather-aggregate + bias --------------------
__global__ __launch_bounds__(256) void aggregate_kernel(
    const int2* __restrict__ packed, const int* __restrict__ row_start,
    const int* __restrict__ rowtot, const unsigned* __restrict__ h2,
    const float* __restrict__ bias, float* __restrict__ out)
{
    int wave = (blockIdx.x * 256 + threadIdx.x) >> 6;
    int lane = threadIdx.x & 63;
    if (wave >= N_NODES) return;

    int start = __builtin_amdgcn_readfirstlane(row_start[wave]);
    int deg   = __builtin_amdgcn_readfirstlane(rowtot[wave]);
    int end   = start + deg;

    const unsigned* hb = h2 + lane;
    float ax = 0.f, ay = 0.f;

    int e = start;
    for (; e + 3 < end; e += 4) {
        int2 p0 = packed[e];
        int2 p1 = packed[e + 1];
        int2 p2 = packed[e + 2];
        int2 p3 = packed[e + 3];
        unsigned u0 = hb[(size_t)p0.x << 6];
        unsigned u1 = hb[(size_t)p1.x << 6];
        unsigned u2 = hb[(size_t)p2.x << 6];
        unsigned u3 = hb[(size_t)p3.x << 6];
        float v0 = __int_as_float(p0.y), v1 = __int_as_float(p1.y);
        float v2 = __int_as_float(p2.y), v3 = __int_as_float(p3.y);
        ax = fmaf(v0, __uint_as_float(u0 << 16), ax);
        ay = fmaf(v0, __uint_as_float(u0 & 0xFFFF0000u), ay);
        ax = fmaf(v1, __uint_as_float(u1 << 16), ax);
        ay = fmaf(v1, __uint_as_float(u1 & 0xFFFF0000u), ay);
        ax = fmaf(v2, __uint_as_float(u2 << 16), ax);
        ay = fmaf(v2, __uint_as_float(u2 & 0xFFFF0000u), ay);
        ax = fmaf(v3, __uint_as_float(u3 << 16), ax);
        ay = fmaf(v3, __uint_as_float(u3 & 0xFFFF0000u), ay);
    }
    for (; e < end; ++e) {
        int2 p0 = packed[e];
        unsigned u0 = hb[(size_t)p0.x << 6];
        float v0 = __int_as_float(p0.y);
        ax = fmaf(v0, __uint_as_float(u0 << 16), ax);
        ay = fmaf(v0, __uint_as_float(u0 & 0xFFFF0000u), ay);
    }

    float2 b = *(const float2*)(bias + lane * 2);
    *(float2*)(out + (size_t)wave * OUT_F + lane * 2) = make_float2(ax + b.x, ay + b.y);
}

// -------------------- launch --------------------
extern "C" void kernel_launch(void* const* d_in, const int* in_sizes, int n_in,
                              void* d_out, int out_size, void* d_ws, size_t ws_size,
                              hipStream_t stream)
{
    const float* x     = (const float*)d_in[0];
    const int*   erow  = (const int*)d_in[1];
    const int*   ecol  = (const int*)d_in[2];
    const float* eval_ = (const float*)d_in[3];
    const float* w     = (const float*)d_in[4];
    const float* bias  = (const float*)d_in[5];
    float*       out   = (float*)d_out;

    // workspace layout (bytes):
    //   h (bf16):    0          .. 25,600,000
    //   tmp:         25,600,000 .. +25,600,000
    //   packed:      51,200,000 .. +25,600,000
    //   cntmat:      76,800,000 .. +800,768   (512 x 391 int)
    //   blockbase:   77,600,768 .. +800,768
    //   tot:         78,401,536 .. +1,568
    //   bucket_base: 78,403,104 .. +1,568     (392 int)
    //   row_start:   78,404,672 .. +400,000
    //   rowtot:      78,804,672 .. +400,000   (total ~79.2 MB)
    char* ws = (char*)d_ws;
    unsigned short* h           = (unsigned short*)(ws);
    int2*           tmp         = (int2*)(ws + 25600000);
    int2*           packed      = (int2*)(ws + 51200000);
    int*            cntmat      = (int*)(ws + 76800000);
    int*            blockbase   = (int*)(ws + 77600768);
    int*            tot         = (int*)(ws + 78401536);
    int*            bucket_base = (int*)(ws + 78403104);
    int*            row_start   = (int*)(ws + 78404672);
    int*            rowtot      = (int*)(ws + 78804672);

    // 1) h = bf16(x @ w) via MFMA
    hipLaunchKernelGGL(gemm_xw_mfma,
                       dim3((N_NODES + 127) / 128), dim3(256), 0, stream,
                       x, w, h);

    // 2) CSR build: two-level bucket sort, LDS atomics only
    hipLaunchKernelGGL(pass_a_kernel, dim3(NBC), dim3(256), 0, stream, erow, cntmat);
    hipLaunchKernelGGL(pass_b_kernel, dim3(NBIN), dim3(256), 0, stream,
                       cntmat, blockbase, tot);
    hipLaunchKernelGGL(pass_b2_kernel, dim3(1), dim3(512), 0, stream, tot, bucket_base);
    hipLaunchKernelGGL(pass_c_kernel, dim3(NBC), dim3(256), 0, stream,
                       erow, ecol, eval_, blockbase, bucket_base, tmp);
    hipLaunchKernelGGL(pass_d_kernel, dim3(NBIN), dim3(256), 0, stream,
                       tmp, bucket_base, packed, row_start, rowtot);

    // 3) aggregate rows + bias
    hipLaunchKernelGGL(aggregate_kernel,
                       dim3((N_NODES * 64 + 255) / 256), dim3(256), 0, stream,
                       packed, row_start, rowtot, (const unsigned*)h, bias, out);
}

// Round 7
// 237.182 us; speedup vs baseline: 1.5927x; 1.0702x over previous
//
#include <hip/hip_runtime.h>

#define N_NODES 100000
#define N_EDGES 3200000
#define IN_F 256
#define OUT_F 128

#define NBIN 391          // coarse bins: row >> 8  (99999>>8 = 390)
#define NBC  512          // coarse pass blocks
#define CHUNK 6272        // edges per coarse block, multiple of 4 (int4 loads)

typedef __attribute__((ext_vector_type(8))) short bf16x8;
typedef __attribute__((ext_vector_type(4))) float f32x4;

union U4BF { uint4 u; bf16x8 v; };

__device__ inline unsigned short f2bf(float f) {
    union { float f; unsigned u; } v; v.f = f;
    unsigned r = v.u + 0x7FFFu + ((v.u >> 16) & 1u);   // round-to-nearest-even
    return (unsigned short)(r >> 16);
}
__device__ inline unsigned pk2(float a, float b) {
    return (unsigned)f2bf(a) | ((unsigned)f2bf(b) << 16);
}

// -------------------- Kernel 0: w -> frag-ordered bf16 --------------------
// Layout: for k-step ks(0..7), col-frag fn(0..7), lane l(0..63): 8 bf16 elems
//   elem e: k = ks*32 + (l>>4)*8 + e, c = fn*16 + (l&15)
// flat uint4 index = ((ks*8 + fn)*64 + l). Wave b-frag reads are lane-consecutive.
__global__ __launch_bounds__(256) void conv_w_kernel(
    const float* __restrict__ w, uint4* __restrict__ wbfF)
{
    int tid = blockIdx.x * 256 + threadIdx.x;   // 0..4095
    int ks = tid >> 9;
    int fn = (tid >> 6) & 7;
    int l  = tid & 63;
    int c  = fn * 16 + (l & 15);
    int k0 = ks * 32 + (l >> 4) * 8;
    const float* wp = w + (size_t)k0 * OUT_F + c;
    uint4 u;
    u.x = pk2(wp[0 * OUT_F], wp[1 * OUT_F]);
    u.y = pk2(wp[2 * OUT_F], wp[3 * OUT_F]);
    u.z = pk2(wp[4 * OUT_F], wp[5 * OUT_F]);
    u.w = pk2(wp[6 * OUT_F], wp[7 * OUT_F]);
    wbfF[tid] = u;
}

// -------------------- Kernel 1: h = bf16(x @ w) via MFMA (v2) --------------------
// 256 thr = 4 waves; block tile 128 rows x 128 cols. B (all K) staged once in LDS
// frag-ordered (conflict-free b128 reads). A-fragments loaded straight from global.
__global__ __launch_bounds__(256) void gemm_xw_mfma(
    const float* __restrict__ x, const uint4* __restrict__ wbfF,
    unsigned short* __restrict__ h)
{
    __shared__ uint4 bsh[4096];   // 64 KB, frag-ordered bf16 B

    const int t    = threadIdx.x;
    const int lane = t & 63;
    const int wid  = t >> 6;
    const int brow = blockIdx.x * 128;
    const int ln   = lane & 15;
    const int kb   = lane >> 4;

    // stage B: one coalesced 64 KB copy
#pragma unroll
    for (int i = 0; i < 16; ++i) bsh[i * 256 + t] = wbfF[i * 256 + t];

    // A row pointers (clamped; garbage rows never written in epilogue)
    int r0 = brow + wid * 32 + ln;
    int r1 = r0 + 16;
    const float* a0p = x + (size_t)(r0 < N_NODES ? r0 : N_NODES - 1) * IN_F;
    const float* a1p = x + (size_t)(r1 < N_NODES ? r1 : N_NODES - 1) * IN_F;

    f32x4 acc[2][8] = {};
    __syncthreads();

#pragma unroll
    for (int ks = 0; ks < 8; ++ks) {
        const int k = ks * 32 + kb * 8;
        U4BF a0, a1;
        {
            float4 p = *(const float4*)(a0p + k);
            float4 q = *(const float4*)(a0p + k + 4);
            a0.u.x = pk2(p.x, p.y); a0.u.y = pk2(p.z, p.w);
            a0.u.z = pk2(q.x, q.y); a0.u.w = pk2(q.z, q.w);
        }
        {
            float4 p = *(const float4*)(a1p + k);
            float4 q = *(const float4*)(a1p + k + 4);
            a1.u.x = pk2(p.x, p.y); a1.u.y = pk2(p.z, p.w);
            a1.u.z = pk2(q.x, q.y); a1.u.w = pk2(q.z, q.w);
        }
        U4BF b[8];
#pragma unroll
        for (int fn = 0; fn < 8; ++fn)
            b[fn].u = bsh[(ks * 8 + fn) * 64 + lane];
#pragma unroll
        for (int fn = 0; fn < 8; ++fn) {
            acc[0][fn] = __builtin_amdgcn_mfma_f32_16x16x32_bf16(
                a0.v, b[fn].v, acc[0][fn], 0, 0, 0);
            acc[1][fn] = __builtin_amdgcn_mfma_f32_16x16x32_bf16(
                a1.v, b[fn].v, acc[1][fn], 0, 0, 0);
        }
    }

    // epilogue: C/D layout col=lane&15, row=(lane>>4)*4+reg
#pragma unroll
    for (int fm = 0; fm < 2; ++fm) {
#pragma unroll
        for (int r = 0; r < 4; ++r) {
            int grow = brow + wid * 32 + fm * 16 + (lane >> 4) * 4 + r;
            if (grow < N_NODES) {
                unsigned short* dst = h + (size_t)grow * OUT_F + ln;
#pragma unroll
                for (int fn = 0; fn < 8; ++fn)
                    dst[fn * 16] = f2bf(acc[fm][fn][r]);
            }
        }
    }
}

// -------------------- Pass A: coarse LDS histogram per block --------------------
__global__ __launch_bounds__(256) void pass_a_kernel(
    const int* __restrict__ erow, int* __restrict__ cntmat)
{
    __shared__ int lhist[512];
    const int t = threadIdx.x;
    const int b = blockIdx.x;
    lhist[t] = 0; lhist[t + 256] = 0;
    __syncthreads();

    const int base = b * CHUNK;
    const int end  = min(base + CHUNK, N_EDGES);
    for (int i = base + t * 4; i < end; i += 1024) {
        int4 r = *(const int4*)(erow + i);
        atomicAdd(&lhist[r.x >> 8], 1);
        atomicAdd(&lhist[r.y >> 8], 1);
        atomicAdd(&lhist[r.z >> 8], 1);
        atomicAdd(&lhist[r.w >> 8], 1);
    }
    __syncthreads();

    int* dst = cntmat + (size_t)b * NBIN;
    for (int j = t; j < NBIN; j += 256) dst[j] = lhist[j];
}

// -------------------- Pass B: per-bin exclusive scan over 512 blocks --------------------
__global__ __launch_bounds__(256) void pass_b_kernel(
    const int* __restrict__ cntmat, int* __restrict__ blockbase,
    int* __restrict__ tot)
{
    __shared__ int sh[256];
    const int t = threadIdx.x;
    const int j = blockIdx.x;
    const int b0 = 2 * t, b1 = 2 * t + 1;
    int c0 = cntmat[(size_t)b0 * NBIN + j];
    int c1 = cntmat[(size_t)b1 * NBIN + j];
    int ps = c0 + c1;
    sh[t] = ps;
    __syncthreads();
    for (int off = 1; off < 256; off <<= 1) {
        int add = (t >= off) ? sh[t - off] : 0;
        __syncthreads();
        sh[t] += add;
        __syncthreads();
    }
    int excl = sh[t] - ps;
    blockbase[(size_t)b0 * NBIN + j] = excl;
    blockbase[(size_t)b1 * NBIN + j] = excl + c0;
    if (t == 255) tot[j] = sh[255];
}

// -------------------- Pass B2: exclusive scan of bucket totals --------------------
__global__ __launch_bounds__(512) void pass_b2_kernel(
    const int* __restrict__ tot, int* __restrict__ bucket_base)
{
    __shared__ int sh[512];
    const int t = threadIdx.x;
    int v = (t < NBIN) ? tot[t] : 0;
    sh[t] = v;
    __syncthreads();
    for (int off = 1; off < 512; off <<= 1) {
        int add = (t >= off) ? sh[t - off] : 0;
        __syncthreads();
        sh[t] += add;
        __syncthreads();
    }
    if (t < NBIN + 1) bucket_base[t] = sh[t] - v;   // exclusive; [NBIN] = N_EDGES
}

// -------------------- Pass C: scatter edges into coarse buckets --------------------
__global__ __launch_bounds__(256) void pass_c_kernel(
    const int* __restrict__ erow, const int* __restrict__ ecol,
    const float* __restrict__ eval_, const int* __restrict__ blockbase,
    const int* __restrict__ bucket_base, int2* __restrict__ tmp)
{
    __shared__ int cur[NBIN];
    const int t = threadIdx.x;
    const int b = blockIdx.x;
    for (int j = t; j < NBIN; j += 256)
        cur[j] = bucket_base[j] + blockbase[(size_t)b * NBIN + j];
    __syncthreads();

    const int base = b * CHUNK;
    const int end  = min(base + CHUNK, N_EDGES);
    for (int i = base + t * 4; i < end; i += 1024) {
        int4   r = *(const int4*)(erow + i);
        int4   c = *(const int4*)(ecol + i);
        float4 v = *(const float4*)(eval_ + i);
        int p0 = atomicAdd(&cur[r.x >> 8], 1);
        tmp[p0] = make_int2(c.x | ((r.x & 255) << 17), __float_as_int(v.x));
        int p1 = atomicAdd(&cur[r.y >> 8], 1);
        tmp[p1] = make_int2(c.y | ((r.y & 255) << 17), __float_as_int(v.y));
        int p2 = atomicAdd(&cur[r.z >> 8], 1);
        tmp[p2] = make_int2(c.z | ((r.z & 255) << 17), __float_as_int(v.z));
        int p3 = atomicAdd(&cur[r.w >> 8], 1);
        tmp[p3] = make_int2(c.w | ((r.w & 255) << 17), __float_as_int(v.w));
    }
}

// -------------------- Pass D: fine sort within bucket -> CSR + row_start/rowtot ----
__global__ __launch_bounds__(256) void pass_d_kernel(
    const int2* __restrict__ tmp, const int* __restrict__ bucket_base,
    int2* __restrict__ packed, int* __restrict__ row_start,
    int* __restrict__ rowtot)
{
    __shared__ int hist[256];
    __shared__ int cursor[256];
    const int t = threadIdx.x;
    const int j = blockIdx.x;
    const int base = bucket_base[j];
    const int end  = bucket_base[j + 1];

    hist[t] = 0;
    __syncthreads();

    for (int i = base + t; i < end; i += 256)
        atomicAdd(&hist[tmp[i].x >> 17], 1);
    __syncthreads();

    int hv = hist[t];
    cursor[t] = hv;
    __syncthreads();
    for (int off = 1; off < 256; off <<= 1) {
        int add = (t >= off) ? cursor[t - off] : 0;
        __syncthreads();
        cursor[t] += add;
        __syncthreads();
    }
    int excl = cursor[t] - hv;

    int r = j * 256 + t;
    if (r < N_NODES) {
        row_start[r] = base + excl;
        rowtot[r]    = hv;
    }
    __syncthreads();
    cursor[t] = excl;
    __syncthreads();

    for (int i = base + t; i < end; i += 256) {
        int2 p = tmp[i];
        int rl = p.x >> 17;
        int pos = atomicAdd(&cursor[rl], 1);
        packed[base + pos] = make_int2(p.x & 0x1FFFF, p.y);
    }
}

// -------------------- Kernel 5: per-row gather-aggregate + bias --------------------
__global__ __launch_bounds__(256) void aggregate_kernel(
    const int2* __restrict__ packed, const int* __restrict__ row_start,
    const int* __restrict__ rowtot, const unsigned* __restrict__ h2,
    const float* __restrict__ bias, float* __restrict__ out)
{
    int wave = (blockIdx.x * 256 + threadIdx.x) >> 6;
    int lane = threadIdx.x & 63;
    if (wave >= N_NODES) return;

    int start = __builtin_amdgcn_readfirstlane(row_start[wave]);
    int deg   = __builtin_amdgcn_readfirstlane(rowtot[wave]);
    int end   = start + deg;

    const unsigned* hb = h2 + lane;
    float ax = 0.f, ay = 0.f;

    int e = start;
    for (; e + 7 < end; e += 8) {
        int2 p0 = packed[e];
        int2 p1 = packed[e + 1];
        int2 p2 = packed[e + 2];
        int2 p3 = packed[e + 3];
        int2 p4 = packed[e + 4];
        int2 p5 = packed[e + 5];
        int2 p6 = packed[e + 6];
        int2 p7 = packed[e + 7];
        unsigned u0 = hb[(size_t)p0.x << 6];
        unsigned u1 = hb[(size_t)p1.x << 6];
        unsigned u2 = hb[(size_t)p2.x << 6];
        unsigned u3 = hb[(size_t)p3.x << 6];
        unsigned u4 = hb[(size_t)p4.x << 6];
        unsigned u5 = hb[(size_t)p5.x << 6];
        unsigned u6 = hb[(size_t)p6.x << 6];
        unsigned u7 = hb[(size_t)p7.x << 6];
        float v0 = __int_as_float(p0.y), v1 = __int_as_float(p1.y);
        float v2 = __int_as_float(p2.y), v3 = __int_as_float(p3.y);
        float v4 = __int_as_float(p4.y), v5 = __int_as_float(p5.y);
        float v6 = __int_as_float(p6.y), v7 = __int_as_float(p7.y);
        ax = fmaf(v0, __uint_as_float(u0 << 16), ax);
        ay = fmaf(v0, __uint_as_float(u0 & 0xFFFF0000u), ay);
        ax = fmaf(v1, __uint_as_float(u1 << 16), ax);
        ay = fmaf(v1, __uint_as_float(u1 & 0xFFFF0000u), ay);
        ax = fmaf(v2, __uint_as_float(u2 << 16), ax);
        ay = fmaf(v2, __uint_as_float(u2 & 0xFFFF0000u), ay);
        ax = fmaf(v3, __uint_as_float(u3 << 16), ax);
        ay = fmaf(v3, __uint_as_float(u3 & 0xFFFF0000u), ay);
        ax = fmaf(v4, __uint_as_float(u4 << 16), ax);
        ay = fmaf(v4, __uint_as_float(u4 & 0xFFFF0000u), ay);
        ax = fmaf(v5, __uint_as_float(u5 << 16), ax);
        ay = fmaf(v5, __uint_as_float(u5 & 0xFFFF0000u), ay);
        ax = fmaf(v6, __uint_as_float(u6 << 16), ax);
        ay = fmaf(v6, __uint_as_float(u6 & 0xFFFF0000u), ay);
        ax = fmaf(v7, __uint_as_float(u7 << 16), ax);
        ay = fmaf(v7, __uint_as_float(u7 & 0xFFFF0000u), ay);
    }
    for (; e < end; ++e) {
        int2 p0 = packed[e];
        unsigned u0 = hb[(size_t)p0.x << 6];
        float v0 = __int_as_float(p0.y);
        ax = fmaf(v0, __uint_as_float(u0 << 16), ax);
        ay = fmaf(v0, __uint_as_float(u0 & 0xFFFF0000u), ay);
    }

    float2 b = *(const float2*)(bias + lane * 2);
    *(float2*)(out + (size_t)wave * OUT_F + lane * 2) = make_float2(ax + b.x, ay + b.y);
}

// -------------------- launch --------------------
extern "C" void kernel_launch(void* const* d_in, const int* in_sizes, int n_in,
                              void* d_out, int out_size, void* d_ws, size_t ws_size,
                              hipStream_t stream)
{
    const float* x     = (const float*)d_in[0];
    const int*   erow  = (const int*)d_in[1];
    const int*   ecol  = (const int*)d_in[2];
    const float* eval_ = (const float*)d_in[3];
    const float* w     = (const float*)d_in[4];
    const float* bias  = (const float*)d_in[5];
    float*       out   = (float*)d_out;

    // workspace layout (bytes):
    //   h (bf16):    0          .. 25,600,000
    //   tmp:         25,600,000 .. +25,600,000
    //   packed:      51,200,000 .. +25,600,000
    //   cntmat:      76,800,000 .. +800,768   (512 x 391 int)
    //   blockbase:   77,600,768 .. +800,768
    //   tot:         78,401,536 .. +1,568
    //   bucket_base: 78,403,104 .. +1,568
    //   row_start:   78,404,672 .. +400,000
    //   rowtot:      78,804,672 .. +400,000
    //   wbfF:        79,204,672 .. +65,536    (total ~79.3 MB)
    char* ws = (char*)d_ws;
    unsigned short* h           = (unsigned short*)(ws);
    int2*           tmp         = (int2*)(ws + 25600000);
    int2*           packed      = (int2*)(ws + 51200000);
    int*            cntmat      = (int*)(ws + 76800000);
    int*            blockbase   = (int*)(ws + 77600768);
    int*            tot         = (int*)(ws + 78401536);
    int*            bucket_base = (int*)(ws + 78403104);
    int*            row_start   = (int*)(ws + 78404672);
    int*            rowtot      = (int*)(ws + 78804672);
    uint4*          wbfF        = (uint4*)(ws + 79204672);

    // 0) w -> frag-ordered bf16
    hipLaunchKernelGGL(conv_w_kernel, dim3(16), dim3(256), 0, stream, w, wbfF);

    // 1) h = bf16(x @ w) via MFMA v2
    hipLaunchKernelGGL(gemm_xw_mfma,
                       dim3((N_NODES + 127) / 128), dim3(256), 0, stream,
                       x, wbfF, h);

    // 2) CSR build: two-level bucket sort, LDS atomics only
    hipLaunchKernelGGL(pass_a_kernel, dim3(NBC), dim3(256), 0, stream, erow, cntmat);
    hipLaunchKernelGGL(pass_b_kernel, dim3(NBIN), dim3(256), 0, stream,
                       cntmat, blockbase, tot);
    hipLaunchKernelGGL(pass_b2_kernel, dim3(1), dim3(512), 0, stream, tot, bucket_base);
    hipLaunchKernelGGL(pass_c_kernel, dim3(NBC), dim3(256), 0, stream,
                       erow, ecol, eval_, blockbase, bucket_base, tmp);
    hipLaunchKernelGGL(pass_d_kernel, dim3(NBIN), dim3(256), 0, stream,
                       tmp, bucket_base, packed, row_start, rowtot);

    // 3) aggregate rows + bias
    hipLaunchKernelGGL(aggregate_kernel,
                       dim3((N_NODES * 64 + 255) / 256), dim3(256), 0, stream,
                       packed, row_start, rowtot, (const unsigned*)h, bias, out);
}